// Round 13
// baseline (58.680 us; speedup 1.0000x reference)
//
#include <hip/hip_runtime.h>
#include <hip/hip_bf16.h>
#include <stdint.h>

// Problem constants (KANLayer): B=8192, I=256, O=256, NUM_BASIS=7, ORDER=3
#define B_SZ 8192
#define I_SZ 256
#define O_SZ 256
#define KDIM 2048   // I_SZ * 8  (7 basis + 1 silu per input feature)
#define BMB 128     // rows per block (4 row-groups x 32)
#define BNB 64      // output cols per block
#define NPART 128   // min/max partial rows

typedef __bf16 bf16x8 __attribute__((ext_vector_type(8)));
typedef float f32x4 __attribute__((ext_vector_type(4)));

// Kernel 1: per-column min/max partials (proven r7 shape).
__global__ __launch_bounds__(256) void minmax_partial(
    const float* __restrict__ x, float* __restrict__ pmin,
    float* __restrict__ pmax) {
  const int cg = threadIdx.x & 63;
  const int rs = threadIdx.x >> 6;
  const int r0 = blockIdx.x * 64;
  const float* p = x + (size_t)(r0 + rs) * I_SZ + cg * 4;
  float4 mn = {1e30f, 1e30f, 1e30f, 1e30f};
  float4 mx = {-1e30f, -1e30f, -1e30f, -1e30f};
#pragma unroll
  for (int k = 0; k < 16; ++k) {
    const float4 v = *reinterpret_cast<const float4*>(p + (size_t)k * 4 * I_SZ);
    mn.x = fminf(mn.x, v.x); mn.y = fminf(mn.y, v.y);
    mn.z = fminf(mn.z, v.z); mn.w = fminf(mn.w, v.w);
    mx.x = fmaxf(mx.x, v.x); mx.y = fmaxf(mx.y, v.y);
    mx.z = fmaxf(mx.z, v.z); mx.w = fmaxf(mx.w, v.w);
  }
  __shared__ float rmn[4][I_SZ], rmx[4][I_SZ];
  *reinterpret_cast<float4*>(&rmn[rs][cg * 4]) = mn;
  *reinterpret_cast<float4*>(&rmx[rs][cg * 4]) = mx;
  __syncthreads();
  if (threadIdx.x < 64) {
    float4 a, b;
    const int c0 = threadIdx.x * 4;
    a.x = fminf(fminf(rmn[0][c0+0], rmn[1][c0+0]), fminf(rmn[2][c0+0], rmn[3][c0+0]));
    a.y = fminf(fminf(rmn[0][c0+1], rmn[1][c0+1]), fminf(rmn[2][c0+1], rmn[3][c0+1]));
    a.z = fminf(fminf(rmn[0][c0+2], rmn[1][c0+2]), fminf(rmn[2][c0+2], rmn[3][c0+2]));
    a.w = fminf(fminf(rmn[0][c0+3], rmn[1][c0+3]), fminf(rmn[2][c0+3], rmn[3][c0+3]));
    b.x = fmaxf(fmaxf(rmx[0][c0+0], rmx[1][c0+0]), fmaxf(rmx[2][c0+0], rmx[3][c0+0]));
    b.y = fmaxf(fmaxf(rmx[0][c0+1], rmx[1][c0+1]), fmaxf(rmx[2][c0+1], rmx[3][c0+1]));
    b.z = fmaxf(fmaxf(rmx[0][c0+2], rmx[1][c0+2]), fmaxf(rmx[2][c0+2], rmx[3][c0+2]));
    b.w = fmaxf(fmaxf(rmx[0][c0+3], rmx[1][c0+3]), fmaxf(rmx[2][c0+3], rmx[3][c0+3]));
    *reinterpret_cast<float4*>(&pmin[blockIdx.x * I_SZ + c0]) = a;
    *reinterpret_cast<float4*>(&pmax[blockIdx.x * I_SZ + c0]) = b;
  }
}

// Kernel 2: pack weights -> Wp[o, i*8+m] bf16, pre-swizzled (unit ^= o&7).
// Pure pack — no serial tail (scale reduce moved into gemm prologue).
__global__ void pack_W(const float* __restrict__ bw,
                       const float* __restrict__ sw,
                       const float* __restrict__ coeff,
                       __hip_bfloat16* __restrict__ W) {
  const int idx = blockIdx.x * blockDim.x + threadIdx.x;
  const int i = idx & (I_SZ - 1);
  const int o = idx >> 8;
  const float s = sw[idx];
  union { __hip_bfloat16 h[8]; float4 f4; } u;
#pragma unroll
  for (int m = 0; m < 7; ++m)
    u.h[m] = __float2bfloat16(coeff[(size_t)idx * 7 + m] * s);
  u.h[7] = __float2bfloat16(bw[idx]);
  const size_t off = (size_t)o * KDIM + (size_t)((i ^ (o & 7)) << 3);
  *reinterpret_cast<float4*>(&W[off]) = u.f4;
}

__device__ __forceinline__ void async16(const __hip_bfloat16* g, __hip_bfloat16* l) {
  __builtin_amdgcn_global_load_lds(
      (const __attribute__((address_space(1))) void*)g,
      (__attribute__((address_space(3))) void*)l, 16, 0, 0);
}

__device__ __forceinline__ uint32_t bfc(float f) {
  union { __hip_bfloat16 b; unsigned short s; } c;
  c.b = __float2bfloat16(f);
  return (uint32_t)c.s;
}

// closed-form uniform cubic B-spline (== reference's truncated de Boor),
// packed into the 8-bf16 A-fragment via 128-bit funnel shift (verified r10-12).
__device__ __forceinline__ bf16x8 evalOne(float xv, float2 s2) {
  const float xn = __builtin_fmaf(xv, s2.x, s2.y);
  const float sp = __builtin_fmaf(xn, 5.0f, 5.0f);
  const float c6 = fminf(fmaxf(floorf(sp), 0.0f), 6.0f);
  const int ci = (int)c6;
  const float u = sp - c6;
  const float zm = (sp > 7.0f) ? 0.0f : (1.0f / 6.0f);
  const float u2 = u * u, u3 = u2 * u, t1 = 1.0f - u;
  const float q3 = u3 * zm;
  const float q0 = (t1 * t1) * (t1 * zm);
  float h2 = __builtin_fmaf(-3.0f, u, 3.0f);
  h2 = __builtin_fmaf(h2, u, 3.0f);
  h2 = __builtin_fmaf(h2, u, 1.0f);                 // -3u^3+3u^2+3u+1
  float h1 = __builtin_fmaf(3.0f, u, -6.0f);
  h1 = __builtin_fmaf(h1, u2, 4.0f);                // 3u^3-6u^2+4
  const float q2v = h2 * zm, q1v = h1 * zm;
  const float silu = xn * __builtin_amdgcn_rcpf(1.0f + __expf(-xn));
  const uint64_t D = (uint64_t)(bfc(q0) | (bfc(q1v) << 16)) |
                     ((uint64_t)(bfc(q2v) | (bfc(q3) << 16)) << 32);
  const int tt = ci * 16 - 48;                      // [-48, 48]
  const uint64_t ls = D << (tt & 63);
  const uint64_t rs = D >> ((-tt) & 63);
  uint64_t lo = (tt >= 0) ? ls : rs;
  uint64_t hi = (tt >= 0) ? ((D >> ((63 - tt) & 63)) >> 1) : 0ull;
  hi = (hi & 0x0000FFFFFFFFFFFFull) | ((uint64_t)bfc(silu) << 48);
  union { uint32_t w[4]; bf16x8 v; } r;
  r.w[0] = (uint32_t)lo; r.w[1] = (uint32_t)(lo >> 32);
  r.w[2] = (uint32_t)hi; r.w[3] = (uint32_t)(hi >> 32);
  return r.v;
}

// Kernel 3: fused basis+GEMM, K-SPLIT WAVES for 2 waves/SIMD.
// Block = 128 rows x 64 cols, 512 threads = 8 waves: wave (wr = w&3, kh = w>>2)
// owns row-group wr (32 rows) x K-half kh (1024 k). A in registers (zero
// in-block eval redundancy; features partition over kh). W dual-region LDS
// (2 x 64KB: kh=0 holds k[0,512), kh=1 holds k[1024,1536)), one mid-kernel
// reload. Zero barriers in the K-loop; pair-waves reduce partial accs via
// LDS at the end.
__global__ __launch_bounds__(512, 2) void gemm_fused(
    const float* __restrict__ x, const __hip_bfloat16* __restrict__ W,
    const float* __restrict__ pmin, const float* __restrict__ pmax,
    const float* __restrict__ bias, float* __restrict__ out) {
  __shared__ __align__(16) __hip_bfloat16 Wlds[2][64][512];  // 128KB
  __shared__ float2 scl[I_SZ];                                // 2KB

  const int t = threadIdx.x;
  const int lane = t & 63;
  const int wave = t >> 6;        // 0..7
  const int wr = wave & 3;        // row group
  const int kh = wave >> 2;       // K half
  const int fr = lane & 15, fk = lane >> 4;

  // XCD swizzle: one XCD covers 8 bm-groups x all 4 bn -> x slice (1MB) and
  // W (1MB) L2-resident per XCD.
  const int bid = blockIdx.x;
  const int swz = (bid & 7) * 32 + (bid >> 3);   // grid 256
  const int bm = swz >> 2, bn = swz & 3;
  const int r0 = bm * BMB, c0 = bn * BNB;

  // W staging: 8 waves x 16 calls = 128 row-stages = [2 regions][64 rows];
  // each call writes one row's 512-k window (1KB, lane-linear).
  auto stageW = [&](int ph) {
#pragma unroll
    for (int c = 0; c < 16; ++c) {
      const int idx = wave * 16 + c;
      const int row = idx & 63, rg = idx >> 6;
      async16(W + (size_t)(c0 + row) * KDIM + rg * 1024 + ph * 512 + lane * 8,
              &Wlds[rg][row][0]);
    }
  };

  stageW(0);

  // scale reduce overlapping stage-0: threads 0-255 reduce MIN of col t,
  // threads 256-511 reduce MAX of col t-256; combined after barrier.
  {
    const int col = t & 255;
    if (t < 256) {
      float v = 1e30f;
#pragma unroll 8
      for (int p = 0; p < NPART; ++p) v = fminf(v, pmin[p * I_SZ + col]);
      scl[col].x = v;
    } else {
      float v = -1e30f;
#pragma unroll 8
      for (int p = 0; p < NPART; ++p) v = fmaxf(v, pmax[p * I_SZ + col]);
      scl[col].y = v;
    }
  }

  // x prefetch for group (ph=0, g=0): features fb0 + {0,4,8,12} + fk
  const float* xq = x + (size_t)(r0 + wr * 32 + fr) * I_SZ + fk;
  const int fb0 = kh * 128;
  float xc[8], xn[8];
#pragma unroll
  for (int s = 0; s < 4; ++s) {
    xc[s]     = xq[fb0 + 4 * s];
    xc[4 + s] = xq[16 * I_SZ + fb0 + 4 * s];
  }

  __syncthreads();    // raw mn/mx visible (stage0 also drained here)
  if (t < 256) {
    const float mn = scl[t].x, mx = scl[t].y;
    const float w = fmaxf(mx - mn, 0.01f);
    const float rhw = 2.0f / w;
    scl[t] = make_float2(rhw, -0.5f * (mx + mn) * rhw);
  }
  __syncthreads();    // final scales visible

  f32x4 acc[2][4] = {{{0,0,0,0},{0,0,0,0},{0,0,0,0},{0,0,0,0}},
                     {{0,0,0,0},{0,0,0,0},{0,0,0,0},{0,0,0,0}}};

#pragma unroll 1
  for (int ph = 0; ph < 2; ++ph) {
    const int fb = fb0 + ph * 64;   // feature base of this phase (64 features)
#pragma unroll 1
    for (int g = 0; g < 4; ++g) {
      // prefetch next group's x (4 k-steps = 16 features, 2 rows)
      if (!(ph == 1 && g == 3)) {
        const int nfb  = (g == 3) ? fb0 + 64 : fb;
        const int noff = (g == 3) ? 0 : (g + 1) * 16;
#pragma unroll
        for (int s = 0; s < 4; ++s) {
          xn[s]     = xq[nfb + noff + 4 * s];
          xn[4 + s] = xq[16 * I_SZ + nfb + noff + 4 * s];
        }
      }
#pragma unroll
      for (int s = 0; s < 4; ++s) {
        const int ksp = g * 4 + s;              // k-step within phase, 0..15
        const float2 sc = scl[fb + ksp * 4 + fk];
        const bf16x8 a0 = evalOne(xc[s], sc);       // row wr*32+fr
        const bf16x8 a1 = evalOne(xc[4 + s], sc);   // row wr*32+fr+16
        const int u = ksp * 4 + fk;             // unit within window, 0..63
        const int grp = u & ~7, low = u & 7;
        bf16x8 bg[4];
#pragma unroll
        for (int n = 0; n < 4; ++n) {
          const int row = n * 16 + fr;
          const int cidx = grp | (low ^ (row & 7));
          bg[n] = *reinterpret_cast<const bf16x8*>(&Wlds[kh][row][cidx * 8]);
        }
#pragma unroll
        for (int n = 0; n < 4; ++n) {
          acc[0][n] = __builtin_amdgcn_mfma_f32_16x16x32_bf16(a0, bg[n], acc[0][n], 0, 0, 0);
          acc[1][n] = __builtin_amdgcn_mfma_f32_16x16x32_bf16(a1, bg[n], acc[1][n], 0, 0, 0);
        }
      }
#pragma unroll
      for (int j = 0; j < 8; ++j) xc[j] = xn[j];
    }
    if (ph == 0) {
      __syncthreads();   // all waves done reading phase-0 windows
      stageW(1);
      __syncthreads();   // phase-1 windows visible (drains vmcnt)
    }
  }

  // epilogue: pair-wave reduce (kh=1 partials -> kh=0) through dead W-LDS.
  __syncthreads();
  float* rbuf = reinterpret_cast<float*>(&Wlds[0][0][0]);
  float* pb = rbuf + wr * 2048 + lane * 32;     // 8KB per row-group
  if (kh == 1) {
#pragma unroll
    for (int m = 0; m < 2; ++m)
#pragma unroll
      for (int n = 0; n < 4; ++n) {
        const int slot = ((m * 4 + n) + lane) & 7;   // rotate: 8-way max
        *reinterpret_cast<f32x4*>(&pb[slot * 4]) = acc[m][n];
      }
  }
  __syncthreads();
  if (kh == 0) {
#pragma unroll
    for (int m = 0; m < 2; ++m)
#pragma unroll
      for (int n = 0; n < 4; ++n) {
        const int slot = ((m * 4 + n) + lane) & 7;
        const f32x4 v = *reinterpret_cast<const f32x4*>(&pb[slot * 4]);
        const int col = c0 + n * 16 + fr;
        const float bc = bias[col];
#pragma unroll
        for (int r = 0; r < 4; ++r) {
          const int row = r0 + wr * 32 + m * 16 + fk * 4 + r;
          out[(size_t)row * O_SZ + col] = acc[m][n][r] + v[r] + bc;
        }
      }
  }
}

extern "C" void kernel_launch(void* const* d_in, const int* in_sizes, int n_in,
                              void* d_out, int out_size, void* d_ws, size_t ws_size,
                              hipStream_t stream) {
  const float* x     = (const float*)d_in[0];
  const float* bw    = (const float*)d_in[1];
  const float* sw    = (const float*)d_in[2];
  const float* coeff = (const float*)d_in[3];
  const float* bias  = (const float*)d_in[4];
  float* out = (float*)d_out;

  char* ws = (char*)d_ws;
  __hip_bfloat16* Wbuf = (__hip_bfloat16*)ws;                    // 1 MiB
  float* pmin = (float*)(ws + (size_t)O_SZ * KDIM * 2);          // 128 KiB
  float* pmax = pmin + NPART * I_SZ;                             // 128 KiB

  minmax_partial<<<NPART, 256, 0, stream>>>(x, pmin, pmax);
  pack_W<<<(O_SZ * I_SZ) / 256, 256, 0, stream>>>(bw, sw, coeff, Wbuf);
  gemm_fused<<<(B_SZ / BMB) * (O_SZ / BNB), 512, 0, stream>>>(x, Wbuf, pmin,
                                                              pmax, bias, out);
}

// Round 14
// 44.886 us; speedup vs baseline: 1.3073x; 1.3073x over previous
//
#include <hip/hip_runtime.h>
#include <hip/hip_bf16.h>

// Problem constants (KANLayer): B=8192, I=256, O=256, NUM_BASIS=7, ORDER=3
#define B_SZ 8192
#define I_SZ 256
#define O_SZ 256
#define KDIM 2048  // I_SZ * 8  (7 basis + 1 silu per input feature)
#define BM 32      // rows per block
#define BN 64      // output cols per block
#define BKT 64     // K per tile = 8 features
#define NT 32      // KDIM / BKT
#define NPART 128  // min/max partial rows

typedef __bf16 bf16x8 __attribute__((ext_vector_type(8)));
typedef float f32x4 __attribute__((ext_vector_type(4)));

// Kernel 1: per-column min/max partials (proven r7 shape).
__global__ __launch_bounds__(256) void minmax_partial(
    const float* __restrict__ x, float* __restrict__ pmin,
    float* __restrict__ pmax) {
  const int cg = threadIdx.x & 63;
  const int rs = threadIdx.x >> 6;
  const int r0 = blockIdx.x * 64;
  const float* p = x + (size_t)(r0 + rs) * I_SZ + cg * 4;
  float4 mn = {1e30f, 1e30f, 1e30f, 1e30f};
  float4 mx = {-1e30f, -1e30f, -1e30f, -1e30f};
#pragma unroll
  for (int k = 0; k < 16; ++k) {
    const float4 v = *reinterpret_cast<const float4*>(p + (size_t)k * 4 * I_SZ);
    mn.x = fminf(mn.x, v.x); mn.y = fminf(mn.y, v.y);
    mn.z = fminf(mn.z, v.z); mn.w = fminf(mn.w, v.w);
    mx.x = fmaxf(mx.x, v.x); mx.y = fmaxf(mx.y, v.y);
    mx.z = fmaxf(mx.z, v.z); mx.w = fmaxf(mx.w, v.w);
  }
  __shared__ float rmn[4][I_SZ], rmx[4][I_SZ];
  *reinterpret_cast<float4*>(&rmn[rs][cg * 4]) = mn;
  *reinterpret_cast<float4*>(&rmx[rs][cg * 4]) = mx;
  __syncthreads();
  if (threadIdx.x < 64) {
    float4 a, b;
    const int c0 = threadIdx.x * 4;
    a.x = fminf(fminf(rmn[0][c0+0], rmn[1][c0+0]), fminf(rmn[2][c0+0], rmn[3][c0+0]));
    a.y = fminf(fminf(rmn[0][c0+1], rmn[1][c0+1]), fminf(rmn[2][c0+1], rmn[3][c0+1]));
    a.z = fminf(fminf(rmn[0][c0+2], rmn[1][c0+2]), fminf(rmn[2][c0+2], rmn[3][c0+2]));
    a.w = fminf(fminf(rmn[0][c0+3], rmn[1][c0+3]), fminf(rmn[2][c0+3], rmn[3][c0+3]));
    b.x = fmaxf(fmaxf(rmx[0][c0+0], rmx[1][c0+0]), fmaxf(rmx[2][c0+0], rmx[3][c0+0]));
    b.y = fmaxf(fmaxf(rmx[0][c0+1], rmx[1][c0+1]), fmaxf(rmx[2][c0+1], rmx[3][c0+1]));
    b.z = fmaxf(fmaxf(rmx[0][c0+2], rmx[1][c0+2]), fmaxf(rmx[2][c0+2], rmx[3][c0+2]));
    b.w = fmaxf(fmaxf(rmx[0][c0+3], rmx[1][c0+3]), fmaxf(rmx[2][c0+3], rmx[3][c0+3]));
    *reinterpret_cast<float4*>(&pmin[blockIdx.x * I_SZ + c0]) = a;
    *reinterpret_cast<float4*>(&pmax[blockIdx.x * I_SZ + c0]) = b;
  }
}

// Kernel 2: pack weights -> Wp[o, i*8+m] bf16, pre-swizzled (unit ^= o&7),
// PLUS (block 0) reduce min/max partials into (rhw, -centre*rhw) — coalesced.
__global__ void pack_W(const float* __restrict__ bw,
                       const float* __restrict__ sw,
                       const float* __restrict__ coeff,
                       __hip_bfloat16* __restrict__ W,
                       const float* __restrict__ pmin,
                       const float* __restrict__ pmax,
                       float* __restrict__ cenrhw) {
  const int idx = blockIdx.x * blockDim.x + threadIdx.x;
  const int i = idx & (I_SZ - 1);
  const int o = idx >> 8;
  const float s = sw[idx];
  union { __hip_bfloat16 h[8]; float4 f4; } u;
#pragma unroll
  for (int m = 0; m < 7; ++m)
    u.h[m] = __float2bfloat16(coeff[(size_t)idx * 7 + m] * s);
  u.h[7] = __float2bfloat16(bw[idx]);
  const size_t off = (size_t)o * KDIM + (size_t)((i ^ (o & 7)) << 3);
  *reinterpret_cast<float4*>(&W[off]) = u.f4;

  if (blockIdx.x == 0) {
    const int c = threadIdx.x;
    float mn = 1e30f, mx = -1e30f;
#pragma unroll 8
    for (int p = 0; p < NPART; ++p) {
      mn = fminf(mn, pmin[p * I_SZ + c]);
      mx = fmaxf(mx, pmax[p * I_SZ + c]);
    }
    const float width = fmaxf(mx - mn, 0.01f);
    const float rhw = 2.0f / width;
    cenrhw[2 * c]     = rhw;
    cenrhw[2 * c + 1] = -0.5f * (mx + mn) * rhw;
  }
}

// ---- async global->LDS 16B copy ----
__device__ __forceinline__ void async16(const __hip_bfloat16* g, __hip_bfloat16* l) {
  __builtin_amdgcn_global_load_lds(
      (const __attribute__((address_space(1))) void*)g,
      (__attribute__((address_space(3))) void*)l, 16, 0, 0);
}

// Kernel 3: fused basis-build + GEMM — r7 structure at 4 blocks/CU.
// Block = 32 rows x 64 cols, 256 threads (2x2 waves, wave tile 16x32).
// Grid 1024 = 4 blocks/CU: cross-block TLP hides the per-iter barrier chain.
// LDS 26KB/block (A 2x4KB dbuf + B 2x8KB dbuf + scl 2KB) -> 104KB/CU.
__global__ __launch_bounds__(256, 4) void gemm_fused(
    const float* __restrict__ x, const __hip_bfloat16* __restrict__ W,
    const float* __restrict__ cenrhw, const float* __restrict__ bias,
    float* __restrict__ out) {
  __shared__ __align__(16) __hip_bfloat16 Alds[2][BM * BKT];   // 2 x 4KB
  __shared__ __align__(16) __hip_bfloat16 Blds[2][BN * BKT];   // 2 x 8KB
  __shared__ float2 scl[I_SZ];                                  // 2KB

  const int t = threadIdx.x;
  const int lane = t & 63;
  const int wave = t >> 6;
  const int wm = wave >> 1, wn = wave & 1;   // 2x2 wave grid
  const int fr = lane & 15, fk = lane >> 4;

  // XCD-aware bijective swizzle (1024 blocks, %8==0); bn-minor: one XCD
  // covers contiguous bm range x all bn -> W fully shared in its L2.
  const int bid = blockIdx.x;
  const int swz = (bid & 7) * 128 + (bid >> 3);
  const int bm = swz >> 2, bn = swz & 3;
  const int r0 = bm * BM, c0 = bn * BN;

  scl[t] = reinterpret_cast<const float2*>(cenrhw)[t];

  // A-build mapping: thread -> (row, feature-within-tile); one eval/thread
  const int arow = t >> 3;   // 0..31
  const int af_  = t & 7;    // 0..7
  const float* xp = x + (size_t)(r0 + arow) * I_SZ + af_;

  // B staging: 512 16B-units (64 rows x 8 segs); thread t covers t and 256+t
  const __hip_bfloat16* gb0 = W + (size_t)(c0 + (t >> 3)) * KDIM + (t & 7) * 8;

  f32x4 acc[2] = {{0.f,0.f,0.f,0.f},{0.f,0.f,0.f,0.f}};

  auto stageB = [&](int buf, int kt) {
    const size_t k0 = (size_t)kt * BKT;
    async16(gb0 + k0,                     &Blds[buf][t * 8]);
    async16(gb0 + k0 + (size_t)32 * KDIM, &Blds[buf][2048 + t * 8]);
  };

  // closed-form uniform cubic B-spline (== reference's truncated de Boor):
  // cell c = floor((xn+1)*5) capped at 6, u = frac; slots c-3..c get q0..q3
  // (x 1/6); zero for sp>7.
  auto buildA = [&](int buf, int kt, float xv) {
    const float2 s2 = scl[kt * 8 + af_];
    const float xn = __builtin_fmaf(xv, s2.x, s2.y);
    const float sp = __builtin_fmaf(xn, 5.0f, 5.0f);
    const float c6 = fminf(floorf(sp), 6.0f);
    const int ci = (int)c6;
    const float u = sp - c6;
    const float zm = (sp > 7.0f) ? 0.0f : (1.0f / 6.0f);
    const float u2 = u * u, u3 = u2 * u, t1 = 1.0f - u;
    const float q3 = u3 * zm;
    const float q0 = (t1 * t1) * (t1 * zm);
    float h2 = __builtin_fmaf(-3.0f, u, 3.0f);
    h2 = __builtin_fmaf(h2, u, 3.0f);
    h2 = __builtin_fmaf(h2, u, 1.0f);                 // -3u^3+3u^2+3u+1
    const float q2 = h2 * zm;
    float h1 = __builtin_fmaf(3.0f, u, -6.0f);
    h1 = __builtin_fmaf(h1, u2, 4.0f);                // 3u^3-6u^2+4
    const float q1 = h1 * zm;
    const float silu = xn * __builtin_amdgcn_rcpf(1.0f + __expf(-xn));
    union { __hip_bfloat16 h[8]; float4 f4; } uu;
#pragma unroll
    for (int j = 0; j < 7; ++j) {
      float v = 0.0f;
      v = (ci == j + 3) ? q0 : v;
      v = (ci == j + 2) ? q1 : v;
      v = (ci == j + 1) ? q2 : v;
      v = (ci == j)     ? q3 : v;
      uu.h[j] = __float2bfloat16(v);
    }
    uu.h[7] = __float2bfloat16(silu);
    const int unit = af_ ^ (arow & 7);
    *reinterpret_cast<float4*>(&Alds[buf][arow * BKT + unit * 8]) = uu.f4;
  };

  auto compute = [&](int buf) {
    bf16x8 af[2], bg[2][2];
#pragma unroll
    for (int kk = 0; kk < 2; ++kk) {
      const int row = wm * 16 + fr;
      const int unit = ((kk << 2) | fk) ^ (row & 7);
      af[kk] = *reinterpret_cast<const bf16x8*>(&Alds[buf][row * BKT + unit * 8]);
    }
#pragma unroll
    for (int n = 0; n < 2; ++n)
#pragma unroll
      for (int kk = 0; kk < 2; ++kk) {
        const int row = wn * 32 + n * 16 + fr;
        const int unit = ((kk << 2) | fk) ^ (row & 7);
        bg[n][kk] = *reinterpret_cast<const bf16x8*>(&Blds[buf][row * BKT + unit * 8]);
      }
#pragma unroll
    for (int kk = 0; kk < 2; ++kk)
#pragma unroll
      for (int n = 0; n < 2; ++n)
        acc[n] = __builtin_amdgcn_mfma_f32_16x16x32_bf16(
            af[kk], bg[n][kk], acc[n], 0, 0, 0);
  };

  // prologue: x for tiles 0,1 loaded early; B tile 0 staged.
  const float xv0 = xp[0];
  float xpf = xp[8];
  __syncthreads();              // scl visible
  stageB(0, 0);
  buildA(0, 0, xv0);
  __syncthreads();              // A written + B staged
  int cur = 0;
  for (int kt = 0; kt < NT - 1; ++kt) {
    stageB(cur ^ 1, kt + 1);
    const float xpf2 = xp[min(kt + 2, NT - 1) * 8];
    buildA(cur ^ 1, kt + 1, xpf);
    compute(cur);
    __syncthreads();
    xpf = xpf2;
    cur ^= 1;
  }
  compute(cur);

  // epilogue: C/D layout col=lane&15, row=(lane>>4)*4+reg  [m89/m91]
#pragma unroll
  for (int n = 0; n < 2; ++n) {
    const int col = c0 + wn * 32 + n * 16 + fr;
    const float bc = bias[col];
#pragma unroll
    for (int r = 0; r < 4; ++r) {
      const int row = r0 + wm * 16 + fk * 4 + r;
      out[(size_t)row * O_SZ + col] = acc[n][r] + bc;
    }
  }
}

extern "C" void kernel_launch(void* const* d_in, const int* in_sizes, int n_in,
                              void* d_out, int out_size, void* d_ws, size_t ws_size,
                              hipStream_t stream) {
  const float* x     = (const float*)d_in[0];
  const float* bw    = (const float*)d_in[1];
  const float* sw    = (const float*)d_in[2];
  const float* coeff = (const float*)d_in[3];
  const float* bias  = (const float*)d_in[4];
  float* out = (float*)d_out;

  char* ws = (char*)d_ws;
  __hip_bfloat16* Wbuf = (__hip_bfloat16*)ws;                    // 1 MiB
  float* pmin   = (float*)(ws + (size_t)O_SZ * KDIM * 2);        // 128 KiB
  float* pmax   = pmin + NPART * I_SZ;                           // 128 KiB
  float* cenrhw = pmax + NPART * I_SZ;                           // 2 KiB

  minmax_partial<<<NPART, 256, 0, stream>>>(x, pmin, pmax);
  pack_W<<<(O_SZ * I_SZ) / 256, 256, 0, stream>>>(bw, sw, coeff, Wbuf,
                                                  pmin, pmax, cenrhw);
  gemm_fused<<<(B_SZ / BM) * (O_SZ / BN), 256, 0, stream>>>(x, Wbuf, cenrhw,
                                                            bias, out);
}